// Round 3
// baseline (415.383 us; speedup 1.0000x reference)
//
#include <hip/hip_runtime.h>
#include <stdint.h>

#define BB 1024
#define SS 512
#define HH 128
#define MM 4            // batch rows per block
#define BLK 256         // 4 waves, 1 block per CU
#define NBLK (BB / MM)  // 256 blocks
#define RS 32           // h-trajectory ring slots (flush every 32 steps)
#define RStr 136        // ring row stride in f16

typedef float f32x4 __attribute__((ext_vector_type(4)));
typedef float f32x2 __attribute__((ext_vector_type(2)));
typedef _Float16 f16x8 __attribute__((ext_vector_type(8)));

#define LO_SCALE 2048.0f
#define LO_INV   (1.0f / 2048.0f)
#define L2E      1.44269504088896f

__device__ __forceinline__ float rcp_fast(float x)  { return __builtin_amdgcn_rcpf(x); }
__device__ __forceinline__ float exp2_fast(float x) { return __builtin_amdgcn_exp2f(x); }

__global__ __launch_bounds__(BLK, 1) void pig_kernel(
    const float* __restrict__ x0, const float* __restrict__ v_seq,
    const float* __restrict__ W_ih, const float* __restrict__ W_hh,
    const float* __restrict__ b_ih, const float* __restrict__ b_hh,
    const float* __restrict__ W_out, const float* __restrict__ b_out,
    const float* __restrict__ W_r1, const float* __restrict__ b_r1,
    const float* __restrict__ W_r2, const float* __restrict__ b_r2,
    float* __restrict__ out)
{
    // hp2: [parity][kk 0..3][quadk 0..3][row' 0..7][8 f16] = 2 KB/parity.
    // row' = 2m+p (m 0..3; p: 0=hi, 1=lo*2048).  MFMA A rows 8..15 mirror rows
    // 0..7 (lane reads row' = col&7) -> acc regs of lane (quad,col):
    // reg g -> row' = 4*(quad&1)+g -> [m_a hi, m_a lo, m_b hi, m_b lo] with
    // m_a = 2*(quad&1), m_b = m_a+1.  Each wave computes ALL 6 gate-col tiles
    // for its j-range (3 gates x 2 tiles): A-fragment reused 6x -> A-read
    // gross per CU halves vs the 8-wave/3-tile variant, same MFMA count.
    __shared__ __align__(16) _Float16 hp2[2][1024];         // 4 KB
    __shared__ __align__(16) _Float16 ring[RS * 4 * RStr];  // 34 KB: [slot][m][j]
    __shared__ __align__(16) float    v_lds[SS * 8];        // 16 KB: [t][m*2+o]
    __shared__ __align__(16) float    xs[RS + 1][8];        // x_pred window (+carry at [0])
    __shared__ __align__(16) float    wpk[64][8];           // {W_r1[u][0..3], b_r1[u], W_r2[0][u], W_r2[1][u], 0}
    __shared__ float xc[2][8];                              // x_prev carry, flush-parity buffered

    const int tid  = threadIdx.x;
    const int wave = tid >> 6;          // 0..3
    const int lane = tid & 63;
    const int quad = lane >> 4;         // k-group for A/B fragments
    const int col  = lane & 15;
    const int row0 = blockIdx.x * MM;
    const int cthi = quad >> 1;         // which col-tile this lane's j is in
    const int ma   = (quad & 1) * 2;    // first batch row this lane handles
    const int j    = wave * 32 + cthi * 16 + col;   // this lane's hidden index

    // ---- W_hh B-fragments: wave w owns gates nt*128 + w*32 .. +31 (2 col-tiles) ----
    f16x8 whi[3][4][2];
#pragma unroll
    for (int nt = 0; nt < 3; ++nt) {
#pragma unroll
        for (int c = 0; c < 2; ++c) {
            const int g = nt * HH + wave * 32 + c * 16 + col;
#pragma unroll
            for (int kk = 0; kk < 4; ++kk) {
                const float* p = W_hh + g * HH + kk * 32 + quad * 8;
                f16x8 fh;
#pragma unroll
                for (int i = 0; i < 8; ++i) fh[i] = (_Float16)p[i];
                whi[nt][kk][c] = fh;
            }
        }
    }

    // ---- gate-math per-lane constants (hidden index j; both states share j) ----
    const float wr0 = W_ih[j*2],        wr1 = W_ih[j*2+1];
    const float wz0 = W_ih[(HH+j)*2],   wz1 = W_ih[(HH+j)*2+1];
    const float wn0 = W_ih[(2*HH+j)*2], wn1 = W_ih[(2*HH+j)*2+1];
    const float br  = b_ih[j]      + b_hh[j];
    const float bz  = b_ih[HH+j]   + b_hh[HH+j];
    const float bni = b_ih[2*HH+j];
    const float bnh = b_hh[2*HH+j];

    // ---- hp2 addressing ----
    const int rbase = quad * 64 + (col & 7) * 8;                       // read (+kk*256)
    const int wbase = (j >> 5) * 256 + ((j >> 3) & 3) * 64 + (quad & 1) * 32 + (j & 7);

    // ---- pass-A constants: group g8 = tid>>3 -> (o, m, tt8); lane-in-group l8 ----
    const int g8  = tid >> 3;           // 0..31
    const int l8  = tid & 7;
    const int oA  = g8 & 1;
    const int mA  = (g8 >> 1) & 3;
    const int tt8 = g8 >> 3;            // 0..3
    float woA[16];
#pragma unroll
    for (int i = 0; i < 16; ++i) woA[i] = W_out[oA * HH + l8 * 16 + i];
    const float boA = b_out[oA];

    // ---- pass-B constants: (tB4, mB, qB) ----
    const int qB  = tid & 3;
    const int mB  = (tid >> 2) & 3;
    const int tB4 = tid >> 4;           // 0..15
    const float b2B = b_r2[qB & 1];

    // ---- init ----
    for (int idx = tid; idx < 2 * 1024; idx += BLK) ((_Float16*)hp2)[idx] = (_Float16)0.0f;
    for (int idx = tid; idx < MM * SS * 2; idx += BLK) {
        const int m = idx >> 10, i = idx & 1023;          // i = t*2 + o
        v_lds[(i >> 1) * 8 + m * 2 + (i & 1)] = v_seq[(size_t)(row0 + m) * (SS * 2) + i];
    }
    if (tid < 64) {   // packed residual-MLP weights
        wpk[tid][0] = W_r1[tid*4];   wpk[tid][1] = W_r1[tid*4+1];
        wpk[tid][2] = W_r1[tid*4+2]; wpk[tid][3] = W_r1[tid*4+3];
        wpk[tid][4] = b_r1[tid];
        wpk[tid][5] = W_r2[tid];     wpk[tid][6] = W_r2[64 + tid];
        wpk[tid][7] = 0.0f;
    }
    if (tid < 8)
        xc[0][tid] = x0[(size_t)(row0 + (tid >> 1)) * 2 + (tid & 1)];
    __syncthreads();

    float hold0 = 0.0f, hold1 = 0.0f;   // h[ma][j], h[ma+1][j]
    f32x4 vv4 = *(const f32x4*)&v_lds[(quad & 1) * 4];   // v[t=0] for both states

    for (int t = 0; t < SS; ++t) {
        const int cur = t & 1, nxt = cur ^ 1;

        // ---------- recurrence: 24 MFMA (3 gates x 4 kk x 2 col-tiles), A reused 6x ----------
        f32x4 a0c0 = {0,0,0,0}, a0c1 = {0,0,0,0};
        f32x4 a1c0 = {0,0,0,0}, a1c1 = {0,0,0,0};
        f32x4 a2c0 = {0,0,0,0}, a2c1 = {0,0,0,0};
        const _Float16* hb = &hp2[cur][rbase];
#pragma unroll
        for (int kk = 0; kk < 4; ++kk) {
            f16x8 af = *(const f16x8*)&hb[kk * 256];
            a0c0 = __builtin_amdgcn_mfma_f32_16x16x32_f16(af, whi[0][kk][0], a0c0, 0, 0, 0);
            a0c1 = __builtin_amdgcn_mfma_f32_16x16x32_f16(af, whi[0][kk][1], a0c1, 0, 0, 0);
            a1c0 = __builtin_amdgcn_mfma_f32_16x16x32_f16(af, whi[1][kk][0], a1c0, 0, 0, 0);
            a1c1 = __builtin_amdgcn_mfma_f32_16x16x32_f16(af, whi[1][kk][1], a1c1, 0, 0, 0);
            a2c0 = __builtin_amdgcn_mfma_f32_16x16x32_f16(af, whi[2][kk][0], a2c0, 0, 0, 0);
            a2c1 = __builtin_amdgcn_mfma_f32_16x16x32_f16(af, whi[2][kk][1], a2c1, 0, 0, 0);
        }
        // pick this lane's col-tile; regs = [ma hi, ma lo, mb hi, mb lo]
        const f32x4 A0 = cthi ? a0c1 : a0c0;
        const f32x4 A1 = cthi ? a1c1 : a1c0;
        const f32x4 A2 = cthi ? a2c1 : a2c0;

        const float gh0a = fmaf(A0[1], LO_INV, A0[0]);
        const float gh1a = fmaf(A1[1], LO_INV, A1[0]);
        const float gh2a = fmaf(A2[1], LO_INV, A2[0]);
        const float gh0b = fmaf(A0[3], LO_INV, A0[2]);
        const float gh1b = fmaf(A1[3], LO_INV, A1[2]);
        const float gh2b = fmaf(A2[3], LO_INV, A2[2]);

        // state a (batch row ma)
        const float raa = gh0a + vv4[0]*wr0 + vv4[1]*wr1 + br;
        const float ra_ = rcp_fast(1.0f + exp2_fast(raa * (-L2E)));
        const float zaa = gh1a + vv4[0]*wz0 + vv4[1]*wz1 + bz;
        const float za_ = rcp_fast(1.0f + exp2_fast(zaa * (-L2E)));
        const float naa = vv4[0]*wn0 + vv4[1]*wn1 + bni + ra_ * (gh2a + bnh);
        const float na_ = fmaf(2.0f, rcp_fast(1.0f + exp2_fast(naa * (-2.0f * L2E))), -1.0f);
        hold0 = fmaf(za_, hold0 - na_, na_);

        // state b (batch row ma+1)
        const float rab = gh0b + vv4[2]*wr0 + vv4[3]*wr1 + br;
        const float rb_ = rcp_fast(1.0f + exp2_fast(rab * (-L2E)));
        const float zab = gh1b + vv4[2]*wz0 + vv4[3]*wz1 + bz;
        const float zb_ = rcp_fast(1.0f + exp2_fast(zab * (-L2E)));
        const float nab = vv4[2]*wn0 + vv4[3]*wn1 + bni + rb_ * (gh2b + bnh);
        const float nb_ = fmaf(2.0f, rcp_fast(1.0f + exp2_fast(nab * (-2.0f * L2E))), -1.0f);
        hold1 = fmaf(zb_, hold1 - nb_, nb_);

        const _Float16 hh0 = (_Float16)hold0;
        const _Float16 hh1 = (_Float16)hold1;
        hp2[nxt][wbase]      = hh0;
        hp2[nxt][wbase + 8]  = (_Float16)((hold0 - (float)hh0) * LO_SCALE);
        hp2[nxt][wbase + 16] = hh1;
        hp2[nxt][wbase + 24] = (_Float16)((hold1 - (float)hh1) * LO_SCALE);
        ring[((t & (RS-1)) * 4 + ma)     * RStr + j] = hh0;   // h_seq[t] for the epilogue
        ring[((t & (RS-1)) * 4 + ma + 1) * RStr + j] = hh1;

        vv4 = *(const f32x4*)&v_lds[((t + 1) & (SS - 1)) * 8 + (quad & 1) * 4];  // prefetch next v

        __syncthreads();

        // ---------- batched epilogue every RS steps ----------
        if ((t & (RS - 1)) == (RS - 1)) {
            const int f  = t >> 5;       // flush index
            const int t0 = t - (RS - 1);

            // pass A: x_pred for the window (8-lane dot groups, 8 passes)
            if (tid < 8) xs[0][tid] = xc[f & 1][tid];
#pragma unroll
            for (int p = 0; p < 8; ++p) {
                const int tt = p * 4 + tt8;
                const f16x8 h0 = *(const f16x8*)&ring[(tt * 4 + mA) * RStr + l8 * 16];
                const f16x8 h1 = *(const f16x8*)&ring[(tt * 4 + mA) * RStr + l8 * 16 + 8];
                float acc = 0.0f;
#pragma unroll
                for (int i = 0; i < 8; ++i) {
                    acc += (float)h0[i] * woA[i];
                    acc += (float)h1[i] * woA[8 + i];
                }
                acc += __shfl_xor(acc, 1, 64);
                acc += __shfl_xor(acc, 2, 64);
                acc += __shfl_xor(acc, 4, 64);
                if (l8 == 0) xs[1 + tt][mA * 2 + oA] = acc + boA;
            }
            __syncthreads();

            // pass B: residual MLP + violations + stores; thread = (tB, mB, qB), 2 chunks
#pragma unroll
            for (int c2 = 0; c2 < 2; ++c2) {
                const int tB = c2 * 16 + tB4;
                const float xp0 = xs[tB][mB*2], xp1 = xs[tB][mB*2+1];
                const f32x2 vt2 = *(const f32x2*)&v_lds[(t0 + tB) * 8 + mB * 2];
                float rss0 = 0.0f, rss1 = 0.0f;
#pragma unroll
                for (int uu = 0; uu < 16; ++uu) {
                    const int u = qB * 16 + uu;
                    const f32x4 wA = *(const f32x4*)&wpk[u][0];
                    const f32x4 wB = *(const f32x4*)&wpk[u][4];
                    const float hu = fmaxf(wB[0] + wA[0]*xp0 + wA[1]*xp1 + wA[2]*vt2[0] + wA[3]*vt2[1], 0.0f);
                    rss0 += hu * wB[1];
                    rss1 += hu * wB[2];
                }
                rss0 += __shfl_xor(rss0, 1, 64);
                rss1 += __shfl_xor(rss1, 1, 64);
                rss0 += __shfl_xor(rss0, 2, 64);
                rss1 += __shfl_xor(rss1, 2, 64);
                if (qB < 2) {
                    const int o = qB;
                    const float xpred = xs[tB + 1][mB*2 + o];
                    const float xpv   = xs[tB][mB*2 + o];
                    const float vv    = v_lds[(t0 + tB) * 8 + mB*2 + o];
                    const float resid = (o ? rss1 : rss0) + b2B;
                    const float viol  = xpred - (xpv + vv + resid);
                    const size_t base = (size_t)(row0 + mB) * (SS * 2) + (t0 + tB) * 2 + o;
                    out[base] = xpred;
                    out[(size_t)BB * SS * 2 + base] = viol;
                }
            }
            if (tid < 8) xc[(f + 1) & 1][tid] = xs[RS][tid];   // carry to next window
            __syncthreads();
        }
    }
}

extern "C" void kernel_launch(void* const* d_in, const int* in_sizes, int n_in,
                              void* d_out, int out_size, void* d_ws, size_t ws_size,
                              hipStream_t stream) {
    pig_kernel<<<dim3(NBLK), dim3(BLK), 0, stream>>>(
        (const float*)d_in[0],  (const float*)d_in[1],  (const float*)d_in[2],
        (const float*)d_in[3],  (const float*)d_in[4],  (const float*)d_in[5],
        (const float*)d_in[6],  (const float*)d_in[7],  (const float*)d_in[8],
        (const float*)d_in[9],  (const float*)d_in[10], (const float*)d_in[11],
        (float*)d_out);
}

// Round 4
// 369.539 us; speedup vs baseline: 1.1241x; 1.1241x over previous
//
#include <hip/hip_runtime.h>
#include <stdint.h>

#define BB 1024
#define SS 512
#define HH 128
#define MM 4            // batch rows per block
#define BLK 512         // 8 waves, 1 block/CU, 2 waves/SIMD
#define NBLK (BB / MM)  // 256 blocks -> 1 per CU
#define RS 32           // h-trajectory ring slots (flush every 32 steps)
#define RStr 136        // ring row stride in f16

typedef float f32x4 __attribute__((ext_vector_type(4)));
typedef float f32x2 __attribute__((ext_vector_type(2)));
typedef _Float16 f16x8 __attribute__((ext_vector_type(8)));

#define LO_SCALE 2048.0f
#define LO_INV   (1.0f / 2048.0f)
#define L2E      1.44269504088896f

__device__ __forceinline__ float rcp_fast(float x)  { return __builtin_amdgcn_rcpf(x); }
__device__ __forceinline__ float exp2_fast(float x) { return __builtin_amdgcn_exp2f(x); }

__global__ __launch_bounds__(BLK, 2) void pig_kernel(
    const float* __restrict__ x0, const float* __restrict__ v_seq,
    const float* __restrict__ W_ih, const float* __restrict__ W_hh,
    const float* __restrict__ b_ih, const float* __restrict__ b_hh,
    const float* __restrict__ W_out, const float* __restrict__ b_out,
    const float* __restrict__ W_r1, const float* __restrict__ b_r1,
    const float* __restrict__ W_r2, const float* __restrict__ b_r2,
    float* __restrict__ out)
{
    // hp2: [parity][kk 0..3][quadk 0..3][row' 0..7][8 f16] = 2 KB/parity.
    // row' = 2m+p (p: 0=hi, 1=lo*2048).  MFMA A rows 8..15 mirror 0..7 via the
    // read mapping rr(col); acc regs [0],[1] give (hi,lo) dots for m=quad.
    // WRITES are b32 pair-packed (lane pairs exchange via shfl_xor) so no two
    // lanes ever write halves of the same word -> no write bank conflicts.
    __shared__ __align__(16) _Float16 hp2[2][1024];         // 4 KB
    __shared__ __align__(16) _Float16 ring[RS * 4 * RStr];  // 34 KB: [slot][m][j]
    __shared__ __align__(16) float    v_lds[SS * 8];        // 16 KB: [t][m*2+o]
    __shared__ __align__(16) float    xs[RS + 1][8];        // x_pred window (+carry at [0])
    __shared__ __align__(16) float    wpk[64][8];           // {W_r1[u][0..3], b_r1[u], W_r2[0][u], W_r2[1][u], 0}
    __shared__ float xc[2][8];                              // x_prev carry, flush-parity buffered

    const int tid  = threadIdx.x;
    const int wave = tid >> 6;
    const int lane = tid & 63;
    const int quad = lane >> 4;         // batch row m for this lane
    const int col  = lane & 15;
    const int row0 = blockIdx.x * MM;
    const int j    = wave * 16 + col;   // this lane's hidden index
    const int odd  = col & 1;

    // ---- W_hh B-fragments (f16): wave w owns gates nt*128 + w*16 .. +15 ----
    f16x8 whi[3][4];
#pragma unroll
    for (int nt = 0; nt < 3; ++nt) {
        const int g = nt * HH + j;
#pragma unroll
        for (int kk = 0; kk < 4; ++kk) {
            const float* p = W_hh + g * HH + kk * 32 + quad * 8;
            f16x8 fh;
#pragma unroll
            for (int i = 0; i < 8; ++i) fh[i] = (_Float16)p[i];
            whi[nt][kk] = fh;
        }
    }

    // ---- gate-math per-lane constants (hidden index j, batch row m=quad) ----
    const float wr0 = W_ih[j*2],        wr1 = W_ih[j*2+1];
    const float wz0 = W_ih[(HH+j)*2],   wz1 = W_ih[(HH+j)*2+1];
    const float wn0 = W_ih[(2*HH+j)*2], wn1 = W_ih[(2*HH+j)*2+1];
    const float br  = b_ih[j]      + b_hh[j];
    const float bz  = b_ih[HH+j]   + b_hh[HH+j];
    const float bni = b_ih[2*HH+j];
    const float bnh = b_hh[2*HH+j];

    // ---- hp2 addressing ----
    // read:  lane (col,quad) -> row' = rr(col) = 2*(col>>2)+(col&1); cols with
    //        col&2 set mirror the same address (free broadcast)
    const int rr    = ((col >> 2) << 1) | (col & 1);
    const int rbase = quad * 64 + rr * 8;               // f16 units (+kk*256)
    // write (b32 pair): even lane -> hi-pair word at row' 2m, odd -> lo-pair at 2m+1
    const int wb32  = (j >> 5) * 256 + ((j >> 3) & 3) * 64 + (2 * quad + odd) * 8 + (col & 6);

    // ---- pass-A constants ----
    const int g8  = tid >> 3;
    const int l8  = tid & 7;
    const int oA  = g8 & 1;
    const int mA  = (g8 >> 1) & 3;
    const int tt8 = g8 >> 3;            // 0..7
    float woA[16];
#pragma unroll
    for (int i = 0; i < 16; ++i) woA[i] = W_out[oA * HH + l8 * 16 + i];
    const float boA = b_out[oA];

    // ---- pass-B constants ----
    const int qB = tid & 3;
    const int mB = (tid >> 2) & 3;
    const int tB = tid >> 4;            // 0..31
    const float b2B = b_r2[qB & 1];

    // ---- init ----
    for (int idx = tid; idx < 2 * 1024; idx += BLK) ((_Float16*)hp2)[idx] = (_Float16)0.0f;
    for (int idx = tid; idx < MM * SS * 2; idx += BLK) {
        const int m = idx >> 10, i = idx & 1023;          // i = t*2 + o
        v_lds[(i >> 1) * 8 + m * 2 + (i & 1)] = v_seq[(size_t)(row0 + m) * (SS * 2) + i];
    }
    if (tid < 64) {   // packed residual-MLP weights
        wpk[tid][0] = W_r1[tid*4];   wpk[tid][1] = W_r1[tid*4+1];
        wpk[tid][2] = W_r1[tid*4+2]; wpk[tid][3] = W_r1[tid*4+3];
        wpk[tid][4] = b_r1[tid];
        wpk[tid][5] = W_r2[tid];     wpk[tid][6] = W_r2[64 + tid];
        wpk[tid][7] = 0.0f;
    }
    if (tid < 8)
        xc[0][tid] = x0[(size_t)(row0 + (tid >> 1)) * 2 + (tid & 1)];
    __syncthreads();

    float hold = 0.0f;   // h[quad][j] in fp32 — the only recurrent state
    f32x2 vv2 = *(const f32x2*)&v_lds[quad * 2];   // prefetched v[t] (t=0)

    for (int t = 0; t < SS; ++t) {
        const int cur = t & 1, nxt = cur ^ 1;

        // ---------- the bare recurrence: 12 MFMA ----------
        f32x4 aH0 = {0,0,0,0}, aH1 = {0,0,0,0}, aH2 = {0,0,0,0};
        const _Float16* hb = &hp2[cur][rbase];
#pragma unroll
        for (int kk = 0; kk < 4; ++kk) {
            f16x8 af = *(const f16x8*)&hb[kk * 256];
            aH0 = __builtin_amdgcn_mfma_f32_16x16x32_f16(af, whi[0][kk], aH0, 0, 0, 0);
            aH1 = __builtin_amdgcn_mfma_f32_16x16x32_f16(af, whi[1][kk], aH1, 0, 0, 0);
            aH2 = __builtin_amdgcn_mfma_f32_16x16x32_f16(af, whi[2][kk], aH2, 0, 0, 0);
        }
        // acc[0] = h_hi . W ; acc[1] = (h_lo*2048) . W  -> exact-h gh
        const float gh0 = fmaf(aH0[1], LO_INV, aH0[0]);
        const float gh1 = fmaf(aH1[1], LO_INV, aH1[0]);
        const float gh2 = fmaf(aH2[1], LO_INV, aH2[0]);

        const float ra = gh0 + vv2[0]*wr0 + vv2[1]*wr1 + br;
        const float r  = rcp_fast(1.0f + exp2_fast(ra * (-L2E)));
        const float za = gh1 + vv2[0]*wz0 + vv2[1]*wz1 + bz;
        const float z  = rcp_fast(1.0f + exp2_fast(za * (-L2E)));
        const float na = vv2[0]*wn0 + vv2[1]*wn1 + bni + r * (gh2 + bnh);
        const float n  = fmaf(2.0f, rcp_fast(1.0f + exp2_fast(na * (-2.0f * L2E))), -1.0f);
        hold = fmaf(z, hold - n, n);

        // ---------- pair-packed b32 writes (no same-word b16 collisions) ----------
        const _Float16 hh = (_Float16)hold;
        const _Float16 hl = (_Float16)((hold - (float)hh) * LO_SCALE);
        const unsigned int uh = (unsigned int)__builtin_bit_cast(unsigned short, hh);
        const unsigned int ul = (unsigned int)__builtin_bit_cast(unsigned short, hl);
        const unsigned int oh = (unsigned int)__shfl_xor((int)uh, 1, 64);  // neighbor hi
        const unsigned int ol = (unsigned int)__shfl_xor((int)ul, 1, 64);  // neighbor lo
        // even lane: (hi_j , hi_j+1) -> row' 2m ; odd lane: (lo_j-1 , lo_j) -> row' 2m+1
        const unsigned int lo16 = odd ? ol : uh;
        const unsigned int hi16 = odd ? ul : oh;
        *(unsigned int*)&hp2[nxt][wb32] = lo16 | (hi16 << 16);
        if (!odd)   // ring pair write: (hh_j, hh_j+1) at even j
            *(unsigned int*)&ring[((t & (RS-1)) * 4 + quad) * RStr + j] = uh | (oh << 16);

        vv2 = *(const f32x2*)&v_lds[((t + 1) & (SS - 1)) * 8 + quad * 2];  // prefetch next v

        __syncthreads();

        // ---------- batched epilogue every RS steps ----------
        if ((t & (RS - 1)) == (RS - 1)) {
            const int f  = t >> 5;       // flush index
            const int t0 = t - (RS - 1);

            // pass A: x_pred for the window (8-lane dot groups, 4 passes)
            if (tid < 8) xs[0][tid] = xc[f & 1][tid];
#pragma unroll
            for (int p = 0; p < 4; ++p) {
                const int tt = p * 8 + tt8;
                const f16x8 h0 = *(const f16x8*)&ring[(tt * 4 + mA) * RStr + l8 * 16];
                const f16x8 h1 = *(const f16x8*)&ring[(tt * 4 + mA) * RStr + l8 * 16 + 8];
                float acc = 0.0f;
#pragma unroll
                for (int i = 0; i < 8; ++i) {
                    acc += (float)h0[i] * woA[i];
                    acc += (float)h1[i] * woA[8 + i];
                }
                acc += __shfl_xor(acc, 1, 64);
                acc += __shfl_xor(acc, 2, 64);
                acc += __shfl_xor(acc, 4, 64);
                if (l8 == 0) xs[1 + tt][mA * 2 + oA] = acc + boA;
            }
            __syncthreads();

            // pass B: residual MLP + violations + stores; thread = (tB, mB, qB)
            {
                const float xp0 = xs[tB][mB*2], xp1 = xs[tB][mB*2+1];
                const f32x2 vt2 = *(const f32x2*)&v_lds[(t0 + tB) * 8 + mB * 2];
                float rss0 = 0.0f, rss1 = 0.0f;
#pragma unroll
                for (int uu = 0; uu < 16; ++uu) {
                    const int u = qB * 16 + uu;
                    const f32x4 wA = *(const f32x4*)&wpk[u][0];
                    const f32x4 wB = *(const f32x4*)&wpk[u][4];
                    const float hu = fmaxf(wB[0] + wA[0]*xp0 + wA[1]*xp1 + wA[2]*vt2[0] + wA[3]*vt2[1], 0.0f);
                    rss0 += hu * wB[1];
                    rss1 += hu * wB[2];
                }
                rss0 += __shfl_xor(rss0, 1, 64);
                rss1 += __shfl_xor(rss1, 1, 64);
                rss0 += __shfl_xor(rss0, 2, 64);
                rss1 += __shfl_xor(rss1, 2, 64);
                if (qB < 2) {
                    const int o = qB;
                    const float xpred = xs[tB + 1][mB*2 + o];
                    const float xpv   = xs[tB][mB*2 + o];
                    const float vv    = v_lds[(t0 + tB) * 8 + mB*2 + o];
                    const float resid = (o ? rss1 : rss0) + b2B;
                    const float viol  = xpred - (xpv + vv + resid);
                    const size_t base = (size_t)(row0 + mB) * (SS * 2) + (t0 + tB) * 2 + o;
                    out[base] = xpred;
                    out[(size_t)BB * SS * 2 + base] = viol;
                }
                if (tid < 8) xc[(f + 1) & 1][tid] = xs[RS][tid];   // carry to next window
            }
            __syncthreads();
        }
    }
}

extern "C" void kernel_launch(void* const* d_in, const int* in_sizes, int n_in,
                              void* d_out, int out_size, void* d_ws, size_t ws_size,
                              hipStream_t stream) {
    pig_kernel<<<dim3(NBLK), dim3(BLK), 0, stream>>>(
        (const float*)d_in[0],  (const float*)d_in[1],  (const float*)d_in[2],
        (const float*)d_in[3],  (const float*)d_in[4],  (const float*)d_in[5],
        (const float*)d_in[6],  (const float*)d_in[7],  (const float*)d_in[8],
        (const float*)d_in[9],  (const float*)d_in[10], (const float*)d_in[11],
        (float*)d_out);
}